// Round 1
// baseline (550.511 us; speedup 1.0000x reference)
//
#include <hip/hip_runtime.h>
#include <hip/hip_fp16.h>

// Graph scaled-dot-product attention, N=50000, E=800000, H=8, D=64.
// seg_sum[n] = Q[n] @ (sum_{e:A_e=n} K[B_e])^T -- only Ksum needed per node.
// k pre-converted to f16 (tolerance is bf16-grid ~0.097) to halve gather bytes.
//
// CSR build REWRITTEN without device-scope atomics (theory: 2x 800k global
// atomics were ~250us due to cross-XCD coherence serialization). Two-level
// bucket sort, LDS atomics only:
//   L1 hist (bucket=A>>8, 196 buckets) -> matrix scan -> L1 scatter to tmp
//   -> L2 per-bucket build writes offsets+srcs directly (owner-computes).
// Requires N <= 65536 (bucket fits 8 bits, B fits 24 bits in packed tmp).

#define ROW 512          // H*D floats per node
#define LPAD 68          // padded LDS row stride (floats), 16B-aligned
#define EPB 2048         // edges per level-1 block (256 thr * 8)
#define SCAN_T 1024

typedef float f4 __attribute__((ext_vector_type(4)));
typedef unsigned int u4 __attribute__((ext_vector_type(4)));

// ---------------- level-1 histogram (LDS atomics) + fused f16 convert ----------------
__global__ __launch_bounds__(256) void histconv_kernel(
    const int* __restrict__ A, int* __restrict__ bh, int E, int HB, int NB,
    const float* __restrict__ k, unsigned int* __restrict__ kh, int total8, int doconv)
{
    __shared__ int h[256];
    int blk = blockIdx.x, t = threadIdx.x;
    if (blk >= HB) {                 // -------- convert part --------
        int i = (blk - HB) * 256 + t;
        if (i >= total8) return;
        const f4* src = (const f4*)k + (size_t)i * 2;
        f4 x0 = __builtin_nontemporal_load(src);       // k f32 read once
        f4 x1 = __builtin_nontemporal_load(src + 1);
        union { __half2 h2; unsigned int u; } c0, c1, c2, c3;
        c0.h2 = __floats2half2_rn(x0.x, x0.y);
        c1.h2 = __floats2half2_rn(x0.z, x0.w);
        c2.h2 = __floats2half2_rn(x1.x, x1.y);
        c3.h2 = __floats2half2_rn(x1.z, x1.w);
        u4 o = {c0.u, c1.u, c2.u, c3.u};
        ((u4*)kh)[i] = o;
        return;
    }
    // -------- histogram part --------
    h[t] = 0;
    __syncthreads();
    int base = blk * EPB + t * 8;
    if (base + 8 <= E) {
        int4 a0 = *(const int4*)(A + base);
        int4 a1 = *(const int4*)(A + base + 4);
        atomicAdd(&h[a0.x >> 8], 1); atomicAdd(&h[a0.y >> 8], 1);
        atomicAdd(&h[a0.z >> 8], 1); atomicAdd(&h[a0.w >> 8], 1);
        atomicAdd(&h[a1.x >> 8], 1); atomicAdd(&h[a1.y >> 8], 1);
        atomicAdd(&h[a1.z >> 8], 1); atomicAdd(&h[a1.w >> 8], 1);
    } else {
        for (int j = 0; j < 8; ++j) { int i = base + j; if (i < E) atomicAdd(&h[A[i] >> 8], 1); }
    }
    __syncthreads();
    if (t < NB) bh[t * HB + blk] = h[t];   // bucket-major matrix
}

// ---------------- single-block exclusive scan of the [NB x HB] matrix ----------------
__global__ __launch_bounds__(SCAN_T) void scanmat_kernel(
    int* __restrict__ bh, int tot, int* __restrict__ offsets, int N, int E)
{
    __shared__ int wsum[SCAN_T / 64];
    int t = threadIdx.x;
    int per = (tot + SCAN_T - 1) / SCAN_T;
    int lo = t * per, hi = lo + per; if (hi > tot) hi = tot; if (lo > tot) lo = tot;
    int s = 0;
    for (int i = lo; i < hi; ++i) s += bh[i];
    int lane = t & 63, w = t >> 6;
    int v = s;
    #pragma unroll
    for (int off = 1; off < 64; off <<= 1) {
        int u = __shfl_up(v, off, 64);
        if (lane >= off) v += u;
    }
    if (lane == 63) wsum[w] = v;
    __syncthreads();
    int bse = 0;
    for (int i = 0; i < w; ++i) bse += wsum[i];
    int run = bse + v - s;                 // exclusive prefix for this thread
    for (int i = lo; i < hi; ++i) { int x = bh[i]; bh[i] = run; run += x; }
    if (t == 0) offsets[N] = E;            // grand total
}

// ---------------- level-1 scatter into bucket order (LDS cursors) ----------------
__global__ __launch_bounds__(256) void scatter1_kernel(
    const int* __restrict__ A, const int* __restrict__ Bp, const int* __restrict__ bh,
    int* __restrict__ tmp, int E, int HB, int NB, int balign)
{
    __shared__ int cur[256];
    int blk = blockIdx.x, t = threadIdx.x;
    if (t < NB) cur[t] = bh[t * HB + blk];
    __syncthreads();
    int base = blk * EPB + t * 8;
    if (base + 8 <= E && balign) {
        int4 a0 = *(const int4*)(A + base);
        int4 a1 = *(const int4*)(A + base + 4);
        int4 b0 = *(const int4*)(Bp + base);
        int4 b1 = *(const int4*)(Bp + base + 4);
        int as[8] = {a0.x, a0.y, a0.z, a0.w, a1.x, a1.y, a1.z, a1.w};
        int bs[8] = {b0.x, b0.y, b0.z, b0.w, b1.x, b1.y, b1.z, b1.w};
        #pragma unroll
        for (int j = 0; j < 8; ++j) {
            int pos = atomicAdd(&cur[as[j] >> 8], 1);      // LDS atomic
            tmp[pos] = ((as[j] & 255) << 24) | bs[j];      // pack (A&255, B)
        }
    } else {
        for (int j = 0; j < 8; ++j) {
            int i = base + j;
            if (i < E) {
                int a = A[i], b = Bp[i];
                int pos = atomicAdd(&cur[a >> 8], 1);
                tmp[pos] = ((a & 255) << 24) | b;
            }
        }
    }
}

// ---------------- level-2: per-bucket offsets + srcs (owner-computes) ----------------
__global__ __launch_bounds__(256) void build_kernel(
    const int* __restrict__ bh, const int* __restrict__ tmp,
    int* __restrict__ offsets, int* __restrict__ srcs, int N, int E, int HB, int NB)
{
    __shared__ int cnt[256];
    __shared__ int wsum[4];
    int g = blockIdx.x, t = threadIdx.x;
    int s = bh[g * HB];
    int e = (g == NB - 1) ? E : bh[(g + 1) * HB];
    cnt[t] = 0;
    __syncthreads();
    for (int i = s + t; i < e; i += 256) atomicAdd(&cnt[(tmp[i] >> 24) & 255], 1);
    __syncthreads();
    int val = cnt[t];
    int lane = t & 63, w = t >> 6;
    int v = val;
    #pragma unroll
    for (int off = 1; off < 64; off <<= 1) {
        int u = __shfl_up(v, off, 64);
        if (lane >= off) v += u;
    }
    if (lane == 63) wsum[w] = v;
    __syncthreads();
    int bse = 0;
    #pragma unroll
    for (int i = 0; i < 4; ++i) if (i < w) bse += wsum[i];
    int excl = bse + v - val;
    int n0 = (g << 8) + t;
    if (n0 < N) offsets[n0] = s + excl;
    __syncthreads();
    cnt[t] = s + excl;                     // reuse as cursor
    __syncthreads();
    for (int i = s + t; i < e; i += 256) {
        int wv = tmp[i];
        int pos = atomicAdd(&cnt[(wv >> 24) & 255], 1);   // LDS atomic
        srcs[pos] = wv & 0xFFFFFF;
    }
}

// ---------------- f16 accumulate helper ----------------
__device__ __forceinline__ void acc8(u4 x, f4& a0, f4& a1) {
    union { unsigned int u; __half2 h; } p0{x.x}, p1{x.y}, p2{x.z}, p3{x.w};
    a0.x += __low2float(p0.h); a0.y += __high2float(p0.h);
    a0.z += __low2float(p1.h); a0.w += __high2float(p1.h);
    a1.x += __low2float(p2.h); a1.y += __high2float(p2.h);
    a1.z += __low2float(p3.h); a1.w += __high2float(p3.h);
}

// ---------------- main (f16 k): one wave per node ----------------
__global__ __launch_bounds__(256) void
node_kernel_f16(const float* __restrict__ q, const unsigned int* __restrict__ kh,
                const float* __restrict__ v, const int* __restrict__ offsets,
                const int* __restrict__ srcs, float* __restrict__ out, int N) {
    __shared__ float lds[4][2 * 8 * LPAD + 64 + 8];
    int lane = threadIdx.x & 63;
    int wid  = threadIdx.x >> 6;
    int n = blockIdx.x * 4 + wid;
    bool active = n < N;

    float* qs = &lds[wid][0];
    float* ks = qs + 8 * LPAD;
    float* ps = ks + 8 * LPAD;

    int start = 0, end = 0;
    if (active) {
        start = __builtin_amdgcn_readfirstlane(offsets[n]);      // wave-uniform -> SGPR
        end   = __builtin_amdgcn_readfirstlane(offsets[n + 1]);
        // stage q early: its latency hides under the gather loop
        int r0 = lane >> 4;
        int dq = (lane & 15) * 4;
        const f4* qn = (const f4*)(q + (size_t)n * ROW);
        f4 q0 = __builtin_nontemporal_load(qn + lane);
        f4 q1 = __builtin_nontemporal_load(qn + 64 + lane);
        *(f4*)(qs + r0 * LPAD + dq)       = q0;
        *(f4*)(qs + (r0 + 4) * LPAD + dq) = q1;
    }

    const u4* kh4 = (const u4*)kh;   // one u4 = 8 halves; one row = 64 u4
    f4 a0 = {0.f, 0.f, 0.f, 0.f}, a1 = {0.f, 0.f, 0.f, 0.f};
    int e = start;
    for (; e + 8 <= end; e += 8) {   // 8 independent 16B loads in flight
        int b0 = srcs[e],     b1 = srcs[e + 1], b2 = srcs[e + 2], b3 = srcs[e + 3];
        int b4 = srcs[e + 4], b5 = srcs[e + 5], b6 = srcs[e + 6], b7 = srcs[e + 7];
        u4 x0 = kh4[(size_t)b0 * 64 + lane];
        u4 x1 = kh4[(size_t)b1 * 64 + lane];
        u4 x2 = kh4[(size_t)b2 * 64 + lane];
        u4 x3 = kh4[(size_t)b3 * 64 + lane];
        u4 x4 = kh4[(size_t)b4 * 64 + lane];
        u4 x5 = kh4[(size_t)b5 * 64 + lane];
        u4 x6 = kh4[(size_t)b6 * 64 + lane];
        u4 x7 = kh4[(size_t)b7 * 64 + lane];
        acc8(x0, a0, a1); acc8(x1, a0, a1); acc8(x2, a0, a1); acc8(x3, a0, a1);
        acc8(x4, a0, a1); acc8(x5, a0, a1); acc8(x6, a0, a1); acc8(x7, a0, a1);
    }
    for (; e + 4 <= end; e += 4) {
        int b0 = srcs[e], b1 = srcs[e + 1], b2 = srcs[e + 2], b3 = srcs[e + 3];
        u4 x0 = kh4[(size_t)b0 * 64 + lane];
        u4 x1 = kh4[(size_t)b1 * 64 + lane];
        u4 x2 = kh4[(size_t)b2 * 64 + lane];
        u4 x3 = kh4[(size_t)b3 * 64 + lane];
        acc8(x0, a0, a1); acc8(x1, a0, a1); acc8(x2, a0, a1); acc8(x3, a0, a1);
    }
    for (; e < end; ++e) {
        u4 x = kh4[(size_t)srcs[e] * 64 + lane];
        acc8(x, a0, a1);
    }

    if (active) {
        // lane holds Ksum flat elems [lane*8, lane*8+8): row g = lane>>3, d = (lane&7)*8+j
        int g = lane >> 3;
        int dbase = (lane & 7) * 8;
        *(f4*)(ks + g * LPAD + dbase)     = a0;
        *(f4*)(ks + g * LPAD + dbase + 4) = a1;
    }
    __syncthreads();

    if (active) {
        int h = lane >> 3, g = lane & 7;
        const f4* qrow = (const f4*)(qs + h * LPAD);
        const f4* krow = (const f4*)(ks + g * LPAD);
        float acc = 0.f;
        #pragma unroll
        for (int i = 0; i < 16; ++i) {
            f4 qa = qrow[i];
            f4 kb = krow[i];
            acc += qa.x * kb.x + qa.y * kb.y + qa.z * kb.z + qa.w * kb.w;
        }
        int cnt = end - start;
        float score = acc / (float)((cnt > 0) ? cnt : 1);
        float mx = score;
        #pragma unroll
        for (int off = 1; off < 8; off <<= 1)
            mx = fmaxf(mx, __shfl_xor(mx, off, 8));
        float ex = __expf(score - mx);
        float sm = ex;
        #pragma unroll
        for (int off = 1; off < 8; off <<= 1)
            sm += __shfl_xor(sm, off, 8);
        ps[h * 8 + g] = ex / sm;
    }
    __syncthreads();

    if (active) {
        int h0 = lane >> 4;
        int dbase = (lane & 15) * 4;
        const float* vb = v + (size_t)n * ROW;
        f4 o0 = {0.f, 0.f, 0.f, 0.f}, o1 = {0.f, 0.f, 0.f, 0.f};
        #pragma unroll
        for (int g = 0; g < 8; ++g) {
            f4 vg = __builtin_nontemporal_load((const f4*)(vb + g * 64 + dbase));
            float p0 = ps[h0 * 8 + g];
            float p1 = ps[(h0 + 4) * 8 + g];
            o0 += p0 * vg;
            o1 += p1 * vg;
        }
        f4* ob = (f4*)(out + (size_t)n * ROW);
        __builtin_nontemporal_store(o0, ob + lane);
        __builtin_nontemporal_store(o1, ob + 64 + lane);
    }
}

// ---------------- fallback (f32 k) if workspace too small ----------------
__global__ __launch_bounds__(256) void
node_kernel_f32(const float* __restrict__ q, const float* __restrict__ k,
                const float* __restrict__ v, const int* __restrict__ offsets,
                const int* __restrict__ srcs, float* __restrict__ out, int N) {
    __shared__ float lds[4][2 * 8 * LPAD + 64 + 8];
    int lane = threadIdx.x & 63;
    int wid  = threadIdx.x >> 6;
    int n = blockIdx.x * 4 + wid;
    bool active = n < N;

    float* qs = &lds[wid][0];
    float* ks = qs + 8 * LPAD;
    float* ps = ks + 8 * LPAD;

    int start = 0, end = 0;
    if (active) { start = offsets[n]; end = offsets[n + 1]; }

    f4 a0 = {0.f, 0.f, 0.f, 0.f}, a1 = {0.f, 0.f, 0.f, 0.f};
    for (int e = start; e < end; ++e) {
        int b = srcs[e];
        const f4* kb = (const f4*)(k + (size_t)b * ROW);
        f4 x0 = kb[lane];
        f4 x1 = kb[64 + lane];
        a0 += x0; a1 += x1;
    }

    if (active) {
        int r0 = lane >> 4;
        int dbase = (lane & 15) * 4;
        *(f4*)(ks + r0 * LPAD + dbase)       = a0;
        *(f4*)(ks + (r0 + 4) * LPAD + dbase) = a1;
        const f4* qn = (const f4*)(q + (size_t)n * ROW);
        f4 q0 = qn[lane], q1 = qn[64 + lane];
        *(f4*)(qs + r0 * LPAD + dbase)       = q0;
        *(f4*)(qs + (r0 + 4) * LPAD + dbase) = q1;
    }
    __syncthreads();

    if (active) {
        int h = lane >> 3, g = lane & 7;
        const f4* qrow = (const f4*)(qs + h * LPAD);
        const f4* krow = (const f4*)(ks + g * LPAD);
        float acc = 0.f;
        #pragma unroll
        for (int i = 0; i < 16; ++i) {
            f4 qa = qrow[i];
            f4 kb = krow[i];
            acc += qa.x * kb.x + qa.y * kb.y + qa.z * kb.z + qa.w * kb.w;
        }
        int cnt = end - start;
        float score = acc / (float)((cnt > 0) ? cnt : 1);
        float mx = score;
        #pragma unroll
        for (int off = 1; off < 8; off <<= 1)
            mx = fmaxf(mx, __shfl_xor(mx, off, 8));
        float ex = __expf(score - mx);
        float sm = ex;
        #pragma unroll
        for (int off = 1; off < 8; off <<= 1)
            sm += __shfl_xor(sm, off, 8);
        ps[h * 8 + g] = ex / sm;
    }
    __syncthreads();

    if (active) {
        int h0 = lane >> 4;
        int dbase = (lane & 15) * 4;
        const float* vb = v + (size_t)n * ROW;
        f4 o0 = {0.f, 0.f, 0.f, 0.f}, o1 = {0.f, 0.f, 0.f, 0.f};
        #pragma unroll
        for (int g = 0; g < 8; ++g) {
            f4 vg = *(const f4*)(vb + g * 64 + dbase);
            float p0 = ps[h0 * 8 + g];
            float p1 = ps[(h0 + 4) * 8 + g];
            o0 += p0 * vg;
            o1 += p1 * vg;
        }
        f4* ob = (f4*)(out + (size_t)n * ROW);
        ob[lane]      = o0;
        ob[64 + lane] = o1;
    }
}

extern "C" void kernel_launch(void* const* d_in, const int* in_sizes, int n_in,
                              void* d_out, int out_size, void* d_ws, size_t ws_size,
                              hipStream_t stream) {
    const float* q  = (const float*)d_in[0];
    const float* k  = (const float*)d_in[1];
    const float* v  = (const float*)d_in[2];
    const int*   ei = (const int*)d_in[3];

    int N = in_sizes[0] / ROW;
    int E = in_sizes[3] / 2;
    const int* A = ei;
    const int* B = ei + E;

    int HB  = (E + EPB - 1) / EPB;      // level-1 blocks (391)
    int NB  = (N + 255) >> 8;           // buckets (196) -- requires N <= 65536
    int TOT = NB * HB;

    // workspace layout (ints), then kh (f16 k) 16B-aligned
    int* offsets = (int*)d_ws;          // N+1
    int* srcs    = offsets + (N + 1);   // E
    int* tmp     = srcs + E;            // E (bucket-ordered packed edges)
    int* bh      = tmp + E;             // NB*HB histogram/scan matrix
    size_t int_words = (size_t)(N + 1) + (size_t)E * 2 + (size_t)TOT;
    size_t kh_off = ((int_words * 4 + 15) & ~(size_t)15);
    unsigned int* kh = (unsigned int*)((char*)d_ws + kh_off);
    size_t need = kh_off + (size_t)N * ROW * 2;
    bool use_f16 = ws_size >= need;

    int total8 = N * (ROW / 8);
    int CONVB  = (total8 + 255) / 256;
    int balign = ((E & 3) == 0) ? 1 : 0;
    float* out = (float*)d_out;

    histconv_kernel<<<HB + (use_f16 ? CONVB : 0), 256, 0, stream>>>(
        A, bh, E, HB, NB, k, kh, total8, use_f16 ? 1 : 0);
    scanmat_kernel<<<1, SCAN_T, 0, stream>>>(bh, TOT, offsets, N, E);
    scatter1_kernel<<<HB, 256, 0, stream>>>(A, B, bh, tmp, E, HB, NB, balign);
    build_kernel<<<NB, 256, 0, stream>>>(bh, tmp, offsets, srcs, N, E, HB, NB);
    if (use_f16) {
        node_kernel_f16<<<(N + 3) / 4, 256, 0, stream>>>(q, kh, v, offsets, srcs, out, N);
    } else {
        node_kernel_f32<<<(N + 3) / 4, 256, 0, stream>>>(q, k, v, offsets, srcs, out, N);
    }
}